// Round 11
// baseline (118.689 us; speedup 1.0000x reference)
//
#include <hip/hip_runtime.h>
#include <hip/hip_bf16.h>

// spatial_attention: out = weights @ P1 + P2
//   P1 = H W1^T ; P2 = H W2^T + bias  (same A-rows -> computed together in kA)
//   Domain uniform (runtime-verified) -> weights fast path: w = relu(dval - dist).
//   K0 : Wbf = bf16(W); k0_check -> {dval, uniform}
//   kA : blocks <1024: dual GEMM -> P1T (transposed bf16) + P2 (row-major bf16)
//        blocks >=1024: k2a weights -> weBuf (pre-scaled bf16)   [streams overlap]
//   k2b: out = weBuf @ P1T + P2. K=256 pure GEMM: A direct from weBuf,
//        sB via global_load_lds (linear dest + pre-swizzled src + XOR reads),
//        4 blocks/CU, XCD-swizzled grid.
// Workspace: Wbf 512KB @0 ; flag @512KB ; P1T 32MB @1MB ; P2 32MB @33MB ; weBuf 32MB @65MB

typedef __attribute__((ext_vector_type(4))) float  f32x4;
typedef __attribute__((ext_vector_type(8))) short  bf16x8;
typedef __attribute__((ext_vector_type(4))) short  bf16x4;

#define EPSC 1e-14f

__device__ __forceinline__ short f2bf(float v) {
  __hip_bfloat16 h = __float2bfloat16(v);
  return *reinterpret_cast<short*>(&h);
}
__device__ __forceinline__ float bf2f(unsigned short u) {
  union { unsigned int i; float f; } c; c.i = ((unsigned int)u) << 16; return c.f;
}
__device__ __forceinline__ void gload16(const void* g, void* l) {
  __builtin_amdgcn_global_load_lds(
      (const __attribute__((address_space(1))) void*)g,
      (__attribute__((address_space(3))) void*)l, 16, 0, 0);
}

// ---------------- K0: W fp32 -> bf16 ----------------
__global__ void k0_pack(const float* __restrict__ W, short* __restrict__ Wbf) {
  int idx = blockIdx.x * 256 + threadIdx.x;
  f32x4 v = *(const f32x4*)(W + (size_t)idx * 4);
  bf16x4 pk;
  pk[0] = f2bf(v[0]); pk[1] = f2bf(v[1]); pk[2] = f2bf(v[2]); pk[3] = f2bf(v[3]);
  *(bf16x4*)(Wbf + (size_t)idx * 4) = pk;
}

// ---------------- K0b: domain uniformity check ----------------
__global__ void k0_check(const float* __restrict__ domain, float* __restrict__ flag) {
  __shared__ int s_ok[4];
  const int t = threadIdx.x;
  float v0 = domain[0];
  bool ok = true;
  for (int x = t; x < 72 * 72; x += 256) ok = ok && (domain[x] == v0);
  unsigned long long m = __ballot(ok);
  if ((t & 63) == 0) s_ok[t >> 6] = (m == ~0ull) ? 1 : 0;
  __syncthreads();
  if (t == 0) {
    flag[0] = v0;
    flag[1] = (s_ok[0] && s_ok[1] && s_ok[2] && s_ok[3]) ? 1.f : 0.f;
  }
}

// ---------------- kA: grid 2048, block 512, LDS 70656 ----------------
// blocks 0..1023  : dual-GEMM. sA = 64 H-rows staged ONCE (both passes share A!).
//                   pass 0: B = W[:, :256]  -> P1T[b][d][j] bf16 (transposed)
//                   pass 1: B = W[:, 256:]  -> P2[b][j][d] = acc + bias, bf16
// blocks 1024..2047: k2a weights, wave-per-row (8 rows/wave x 8 waves = 64 rows).
__global__ __launch_bounds__(512) void kA(
    const float* __restrict__ H, const short* __restrict__ Wbf,
    const float* __restrict__ bias, const float* __restrict__ dist,
    const float* __restrict__ bear, const float* __restrict__ head,
    const float* __restrict__ seqmask, const float* __restrict__ domain,
    const float* __restrict__ uflag,
    short* __restrict__ P1T, short* __restrict__ P2, short* __restrict__ weBuf) {
  extern __shared__ char sm[];
  const int t = threadIdx.x;

  if (blockIdx.x < 1024) {
    // ================= dual-GEMM part =================
    char* sA = sm;                       // 64 rows x 256 k bf16, 528B stride
    char* sB = sm + 33792;               // 256 d x 64 k bf16, 144B stride
    const int n0 = blockIdx.x * 64;
    const int b  = n0 >> 8;
    const int jb = n0 & 255;

    // stage sA once (fp32 -> bf16)
    #pragma unroll
    for (int p = 0; p < 4; ++p) {
      int z = t + 512 * p;               // 0..2047 : j = z>>5, seg = z&31
      int j = z >> 5, seg = z & 31;
      const float* src = H + (size_t)(n0 + j) * 256 + seg * 8;
      f32x4 h0 = *(const f32x4*)src;
      f32x4 h1 = *(const f32x4*)(src + 4);
      bf16x8 pk;
      pk[0] = f2bf(h0[0]); pk[1] = f2bf(h0[1]); pk[2] = f2bf(h0[2]); pk[3] = f2bf(h0[3]);
      pk[4] = f2bf(h1[0]); pk[5] = f2bf(h1[1]); pk[6] = f2bf(h1[2]); pk[7] = f2bf(h1[3]);
      *(bf16x8*)(sA + j * 528 + seg * 16) = pk;
    }

    const int wid = t >> 6, l = t & 63;
    const int wn = wid >> 2, wc = wid & 3;     // 2 x 32 rows, 4 x 64 d
    const int lr = l & 15, lg = l >> 4;

    #pragma unroll
    for (int pass = 0; pass < 2; ++pass) {
      f32x4 acc[2][4] = {};
      for (int kk = 0; kk < 256; kk += 64) {
        __syncthreads();                 // prev chunk consumed (and sA ready at first)
        #pragma unroll
        for (int p = 0; p < 4; ++p) {
          int z = t + 512 * p;           // d = z>>3, s = z&7
          int d = z >> 3, s = z & 7;
          bf16x8 v = *(const bf16x8*)(Wbf + (size_t)d * 512 + pass * 256 + kk + s * 8);
          *(bf16x8*)(sB + d * 144 + s * 16) = v;
        }
        __syncthreads();
        #pragma unroll
        for (int sub = 0; sub < 2; ++sub) {
          bf16x8 a[2], bb[4];
          #pragma unroll
          for (int m = 0; m < 2; ++m) {
            int row = wn * 32 + m * 16 + lr;
            a[m] = *(const bf16x8*)(sA + row * 528 + (kk + sub * 32 + lg * 8) * 2);
          }
          #pragma unroll
          for (int f = 0; f < 4; ++f) {
            int d = wc * 64 + f * 16 + lr;
            bb[f] = *(const bf16x8*)(sB + d * 144 + sub * 64 + lg * 16);
          }
          #pragma unroll
          for (int m = 0; m < 2; ++m) {
            #pragma unroll
            for (int f = 0; f < 4; ++f)
              acc[m][f] = __builtin_amdgcn_mfma_f32_16x16x32_bf16(a[m], bb[f], acc[m][f], 0, 0, 0);
          }
        }
      }
      // epilogue
      if (pass == 0) {
        #pragma unroll
        for (int m = 0; m < 2; ++m) {
          int jl = wn * 32 + m * 16 + lg * 4;
          #pragma unroll
          for (int f = 0; f < 4; ++f) {
            int d = wc * 64 + f * 16 + lr;
            f32x4 v = acc[m][f];
            bf16x4 pk;
            pk[0] = f2bf(v[0]); pk[1] = f2bf(v[1]); pk[2] = f2bf(v[2]); pk[3] = f2bf(v[3]);
            *(bf16x4*)(P1T + (size_t)b * 65536 + (size_t)d * 256 + jb + jl) = pk;
          }
        }
      } else {
        #pragma unroll
        for (int m = 0; m < 2; ++m) {
          int jl = wn * 32 + m * 16 + lg * 4;
          #pragma unroll
          for (int f = 0; f < 4; ++f) {
            int d = wc * 64 + f * 16 + lr;
            float bs = bias[d];
            f32x4 v = acc[m][f];
            #pragma unroll
            for (int r = 0; r < 4; ++r)
              P2[(size_t)b * 65536 + (size_t)(jb + jl + r) * 256 + d] = f2bf(v[r] + bs);
          }
        }
      }
    }
  } else {
    // ================= weights part (k2a) =================
    float* sMask = (float*)sm;
    const int idx = blockIdx.x - 1024;
    const int b  = idx >> 2;
    const int i0 = (idx & 3) * 64;
    if (t < 256) sMask[t] = seqmask[b * 256 + t];
    __syncthreads();

    const int w = t >> 6, l = t & 63;
    const int j0 = l * 4;
    const float dval = uflag[0];
    const bool  uni  = uflag[1] != 0.f;
    const f32x4 mj = *(const f32x4*)(sMask + j0);

    f32x4 dv[8];
    #pragma unroll
    for (int rr = 0; rr < 8; ++rr) {
      int i = i0 + w * 8 + rr;
      dv[rr] = *(const f32x4*)(dist + ((size_t)b * 256 + i) * 256 + j0);
    }

    #pragma unroll
    for (int rr = 0; rr < 8; ++rr) {
      const int i = i0 + w * 8 + rr;
      const float mI = sMask[i];
      const size_t base = ((size_t)b * 256 + i) * 256;
      float ev[4];
      float rs = 0.f;
      if (uni) {
        #pragma unroll
        for (int e = 0; e < 4; ++e) {
          float wv = fmaxf(dval - dv[rr][e], 0.f);
          bool valid = (i != j0 + e) && (mI != 0.f) && (mj[e] != 0.f);
          float ex = (wv > 0.f) ? __expf(wv) : 0.f;
          ex = valid ? ex : 0.f;
          rs += ex;
          ev[e] = valid ? (ex + EPSC) : 0.f;
        }
      } else {
        f32x4 bv = *(const f32x4*)(bear + base + j0);
        f32x4 hv = *(const f32x4*)(head + base + j0);
        #pragma unroll
        for (int e = 0; e < 4; ++e) {
          float f1 = fminf(fmaxf(floorf((hv[e] + 2.5f) * 0.2f), 0.f), 71.f);
          float f2 = fminf(fmaxf(floorf((bv[e] + 2.5f) * 0.2f), 0.f), 71.f);
          float wv = fmaxf(domain[(int)(f1 * 72.f + f2)] - dv[rr][e], 0.f);
          bool valid = (i != j0 + e) && (mI != 0.f) && (mj[e] != 0.f);
          float ex = (wv > 0.f) ? __expf(wv) : 0.f;
          ex = valid ? ex : 0.f;
          rs += ex;
          ev[e] = valid ? (ex + EPSC) : 0.f;
        }
      }
      rs += __shfl_xor(rs, 1, 64);
      rs += __shfl_xor(rs, 2, 64);
      rs += __shfl_xor(rs, 4, 64);
      rs += __shfl_xor(rs, 8, 64);
      rs += __shfl_xor(rs, 16, 64);
      rs += __shfl_xor(rs, 32, 64);
      const float scale = 1.0f / (rs + 257.0f * EPSC);
      bf16x4 pk;
      pk[0] = f2bf(ev[0] * scale); pk[1] = f2bf(ev[1] * scale);
      pk[2] = f2bf(ev[2] * scale); pk[3] = f2bf(ev[3] * scale);
      *(bf16x4*)(weBuf + base + j0) = pk;
    }
  }
}

// ---------------- K2b: out = weBuf @ P1T + P2, K=256 ----------------
// grid 1024 (XCD-swizzled: quarters of each b share an XCD), block 512.
// 8 waves: wr = wid&3 (4 x 16 rows), wc = wid>>2 (2 x 128 d); acc[8].
// A direct from weBuf (bf16, L2/L3-hot). sB [256][128] linear via global_load_lds
// (pre-swizzled source slots, XOR-swizzled reads). LDS 32768 -> 4 blocks/CU.
__global__ __launch_bounds__(512) void k2b_gemm(
    const short* __restrict__ weBuf, const short* __restrict__ P1T,
    const short* __restrict__ P2, float* __restrict__ out) {
  extern __shared__ char sm[];
  char* sB = sm;
  const int t = threadIdx.x;
  const int x = blockIdx.x;
  const int blk = (x & 7) * 128 + (x >> 3);    // bijective: 1024 = 8*128
  const int b  = blk >> 2;
  const int i0 = (blk & 3) * 64;

  const int wid = t >> 6, l = t & 63;
  const int lr = l & 15, lg = l >> 4;
  const int wr = wid & 3, wc = wid >> 2;
  const int r3 = l >> 3, sl = l & 7;
  const int sswz = (sl ^ r3) * 8;              // source slot pre-swizzle (shorts)
  const int sw = (lr & 7) << 4;                // read-side XOR (bytes)

  const short* __restrict__ P1b = P1T + (size_t)b * 65536;
  const int i = i0 + wr * 16 + lr;
  const size_t abase = ((size_t)b * 256 + i) * 256;

  f32x4 acc[8] = {};

  for (int c = 0; c < 4; ++c) {
    const int kk = c * 64;
    #pragma unroll
    for (int p = 0; p < 4; ++p) {
      int dd = wid * 8 + r3 + 64 * p;
      gload16(P1b + (size_t)dd * 256 + kk + sswz, sB + (wid * 8 + 64 * p) * 128);
    }
    __syncthreads();                           // vmcnt(0) drain by compiler
    #pragma unroll
    for (int sub = 0; sub < 2; ++sub) {
      bf16x8 av = *(const bf16x8*)(weBuf + abase + kk + sub * 32 + lg * 8);
      #pragma unroll
      for (int n = 0; n < 8; ++n) {
        const int d = wc * 128 + n * 16 + lr;
        bf16x8 bb = *(const bf16x8*)(sB + d * 128 + ((sub * 64 + lg * 16) ^ sw));
        acc[n] = __builtin_amdgcn_mfma_f32_16x16x32_bf16(av, bb, acc[n], 0, 0, 0);
      }
    }
    __syncthreads();                           // all waves done reading sB
  }

  // epilogue: + P2 (bias already folded in), fp32 store
  #pragma unroll
  for (int n = 0; n < 8; ++n) {
    const int d = wc * 128 + n * 16 + lr;
    #pragma unroll
    for (int r = 0; r < 4; ++r) {
      const int row = i0 + wr * 16 + lg * 4 + r;
      const size_t off = ((size_t)b * 256 + row) * 256 + d;
      out[off] = acc[n][r] + bf2f((unsigned short)P2[off]);
    }
  }
}

extern "C" void kernel_launch(void* const* d_in, const int* in_sizes, int n_in,
                              void* d_out, int out_size, void* d_ws, size_t ws_size,
                              hipStream_t stream) {
  const float* hidden  = (const float*)d_in[0];
  const float* dist    = (const float*)d_in[1];
  const float* bear    = (const float*)d_in[2];
  const float* head    = (const float*)d_in[3];
  const float* seqmask = (const float*)d_in[4];
  const float* domain  = (const float*)d_in[5];
  const float* W       = (const float*)d_in[6];
  const float* bias    = (const float*)d_in[7];
  float* out = (float*)d_out;

  char* ws = (char*)d_ws;
  short* Wbf   = (short*)ws;                                 // 512 KB
  float* flag  = (float*)(ws + 524288);                      // 2 floats
  short* P1T   = (short*)(ws + (1u << 20));                  // 32 MB
  short* P2    = (short*)(ws + (1u << 20) + (32u << 20));    // 32 MB
  short* weBuf = (short*)(ws + (1u << 20) + (64u << 20));    // 32 MB

  k0_pack<<<128, 256, 0, stream>>>(W, Wbf);
  k0_check<<<1, 256, 0, stream>>>(domain, flag);
  kA<<<2048, 512, 70656, stream>>>(hidden, Wbf, bias, dist, bear, head,
                                   seqmask, domain, flag, P1T, P2, weBuf);
  k2b_gemm<<<1024, 512, 32768, stream>>>(weBuf, P1T, P2, out);
}